// Round 5
// baseline (317.715 us; speedup 1.0000x reference)
//
#include <hip/hip_runtime.h>
#include <hip/hip_bf16.h>

// Problem constants: x (B,N,D) fp32; per-head SwiGLU FFN H=512.
#define B_ 8192
#define N_ 16
#define D_ 256
#define H_ 512

using bf16x8 = __attribute__((ext_vector_type(8))) short;
using f32x4  = __attribute__((ext_vector_type(4))) float;

__device__ __forceinline__ void gload_lds16(const void* g, void* l) {
    __builtin_amdgcn_global_load_lds(
        (const __attribute__((address_space(1))) void*)g,
        (__attribute__((address_space(3))) void*)l, 16, 0, 0);
}

__device__ __forceinline__ short f2bf(float f) {
    unsigned int u = __float_as_uint(f);
    u += 0x7fffu + ((u >> 16) & 1u);   // round-to-nearest-even
    return (short)(u >> 16);
}

__device__ __forceinline__ float bf2f(short s) {
    return __uint_as_float(((unsigned int)(unsigned short)s) << 16);
}

__device__ __forceinline__ unsigned int pack2(float lo, float hi) {
    return (unsigned int)(unsigned short)f2bf(lo)
         | ((unsigned int)(unsigned short)f2bf(hi) << 16);
}

// ---------------------------------------------------------------------------
// Generic swizzled staging: panel [ROWS x GRANS granules] (granule = 8 bf16 =
// 16B). LDS linear dest; global source pre-swizzled so that LDS[dr][gd] holds
// global granule (gd&~7)|((gd^dr)&7).  Readers use the same involution.
// 512 threads.
// ---------------------------------------------------------------------------
template<int ROWS, int GRANS>
__device__ __forceinline__ void stage_g(const short* __restrict__ g, int gstride,
                                        int colBase, short* lds, int t) {
#pragma unroll
    for (int rnd = 0; rnd < (ROWS * GRANS) / 512; ++rnd) {
        int flat = rnd * 512 + t;
        int dr = flat / GRANS;
        int gd = flat % GRANS;
        int sg = (gd & ~7) | ((gd ^ dr) & 7);
        gload_lds16(g + (size_t)dr * gstride + colBase + sg * 8, &lds[flat * 8]);
    }
}

// ---------------------------------------------------------------------------
// k_prep: fp32 weights -> bf16.
//   wgu layout: [n][chunk c(8)][128 rows][256 d] where chunk row =
//     ((h>>4)&3)*32 + which*16 + (h&15),  which 0=W1,1=W3, c = h>>6.
//     (row-major K=256 contiguous: B^T of (D,H), G/U 16-row interleaved)
//   w2t layout: [n][d][h]  (B^T of (H,D))
// ---------------------------------------------------------------------------
__global__ __launch_bounds__(256) void k_prep(const float* __restrict__ w1,
                                              const float* __restrict__ w3,
                                              const float* __restrict__ w2,
                                              short* __restrict__ wgu,
                                              short* __restrict__ w2t) {
    int o = blockIdx.x * 256 + threadIdx.x;      // 0 .. N*D*H-1 (2M)
    int n = o >> 17;                              // / (D*H = 131072)
    int r = o & 131071;
    int h = r >> 8, d = r & 255;
    size_t g1 = ((size_t)(n * 8 + (h >> 6)) * 128
                 + ((h >> 4) & 3) * 32 + (h & 15)) * 256 + d;
    wgu[g1]        = f2bf(w1[(size_t)n * 131072 + (size_t)d * 512 + h]);
    wgu[g1 + 4096] = f2bf(w3[(size_t)n * 131072 + (size_t)d * 512 + h]);
    int d2 = r >> 9, h2 = r & 511;                // [n][d][h] out layout
    w2t[o] = f2bf(w2[(size_t)n * 131072 + (size_t)h2 * 256 + d2]);
}

// ---------------------------------------------------------------------------
// k_mix: per-b block. rmsnorm1 -> head_mixing -> +x -> rmsnorm2.
// Writes pb (bf16) and pn (bf16), both head-major [head][b][d].
// ---------------------------------------------------------------------------
__global__ __launch_bounds__(256) void k_mix(const float* __restrict__ x,
                                             const float* __restrict__ n1w,
                                             const float* __restrict__ n2w,
                                             short* __restrict__ pb_ws,
                                             short* __restrict__ pn_ws) {
    __shared__ float xs[N_ * D_];
    __shared__ float ps[N_ * D_];
    __shared__ float inv1[N_];
    __shared__ float inv2[N_];
    int b = blockIdx.x;
    int t = threadIdx.x;

    const float4* xb4 = (const float4*)(x + (size_t)b * (N_ * D_));
    float4* xs4 = (float4*)xs;
#pragma unroll
    for (int i = 0; i < 4; ++i) xs4[t + i * 256] = xb4[t + i * 256];
    __syncthreads();

    int hh = t >> 4, sub = t & 15;
    float s = 0.f;
#pragma unroll
    for (int j = 0; j < 16; ++j) { float v = xs[hh * 256 + sub * 16 + j]; s += v * v; }
    s += __shfl_xor(s, 1); s += __shfl_xor(s, 2);
    s += __shfl_xor(s, 4); s += __shfl_xor(s, 8);
    if (sub == 0) inv1[hh] = rsqrtf(s * (1.0f / 256.0f) + 1e-6f);
    __syncthreads();

    {
        int n = t >> 4, j = t & 15;               // d = t
#pragma unroll 1
        for (int m = 0; m < 16; ++m) {
            float v = xs[n * 256 + m * 16 + j] * inv1[n] * n1w[m * 16 + j]
                    + xs[m * 256 + t];
            ps[m * 256 + t] = v;
        }
    }
    __syncthreads();

    float s2 = 0.f;
#pragma unroll
    for (int j = 0; j < 16; ++j) { float v = ps[hh * 256 + sub * 16 + j]; s2 += v * v; }
    s2 += __shfl_xor(s2, 1); s2 += __shfl_xor(s2, 2);
    s2 += __shfl_xor(s2, 4); s2 += __shfl_xor(s2, 8);
    if (sub == 0) inv2[hh] = rsqrtf(s2 * (1.0f / 256.0f) + 1e-6f);
    __syncthreads();

#pragma unroll 1
    for (int m = 0; m < 16; ++m) {
        float v = ps[m * 256 + t];
        size_t off = ((size_t)m * B_ + b) * D_ + t;
        pb_ws[off] = f2bf(v);
        pn_ws[off] = f2bf(v * inv2[m] * n2w[t]);
    }
}

// ---------------------------------------------------------------------------
// k_ffn: fused per-head SwiGLU FFN + residual.
// Block = (head, 64 b-rows), 512 threads (8 waves).  Dynamic LDS 128 KiB:
//   [0,64K): weight stream double-buffer (2 x 32K); overlaid by reduce bufs
//   [64K,128K): hact[64 m][512 h] bf16, granule-XOR swizzled
// Phase A (gate/up, swapped mfma(W,P)): waves = 2 m-groups x 4 h-groups;
//   P (pn rows) in registers -> zero LDS reads for the B operand.
// Phase B (down): waves = 4 d-groups x 2 k-parities; wave tile 64m x 64d;
//   k-parity partial sums pair-reduced through LDS; + residual pb.
// ---------------------------------------------------------------------------
__global__ __launch_bounds__(512, 2) void k_ffn(const short* __restrict__ pn,
                                                const short* __restrict__ wgu,
                                                const short* __restrict__ w2t,
                                                const short* __restrict__ pb,
                                                float* __restrict__ out) {
    extern __shared__ char smem[];
    short* sbuf0 = (short*)smem;               // 16384 shorts
    short* sbuf1 = (short*)(smem + 32768);
    short* hact  = (short*)(smem + 65536);     // 32768 shorts
    float* red   = (float*)smem;               // overlays sbufs (epilogue only)

    // XCD-aware bijective swizzle: 2048 blocks, 256 per XCD chunk.
    int bid = blockIdx.x;
    int bx = (bid & 7) * 256 + (bid >> 3);
    int head = bx >> 7;            // 128 m-tiles per head
    int mtB = (bx & 127) * 64;

    int t = threadIdx.x;
    int w = t >> 6, lane = t & 63;
    int l16 = lane & 15, kq = lane >> 4;

    const short* wguH = wgu + (size_t)head * (8 * 128 * 256);
    const short* w2H  = w2t + (size_t)head * (D_ * H_);

    // ---- phase A roles ----
    int mg = w >> 2;               // 0..1  (32 m-rows each)
    int hg = w & 3;                // 0..3  (16 real h per chunk each)

    // P registers: bopP[mf][kt]  row = mtB + mg*32 + mf*16 + l16, k = kt*32+kq*8
    bf16x8 P[2][8];
#pragma unroll
    for (int mf = 0; mf < 2; ++mf) {
        const short* prow = pn + ((size_t)head * B_ + mtB + mg * 32 + mf * 16 + l16) * D_;
#pragma unroll
        for (int kt = 0; kt < 8; ++kt)
            P[mf][kt] = *(const bf16x8*)(prow + kt * 32 + kq * 8);
    }

    // prologue: stage chunk0 kh0
    stage_g<128, 16>(wguH, 256, 0, sbuf0, t);
    __syncthreads();

    int rowG = hg * 32 + l16;      // G rows within chunk
    int rowU = rowG + 16;          // U rows

#pragma unroll 1
    for (int c = 0; c < 8; ++c) {
        const short* cbase = wguH + (size_t)c * (128 * 256);
        f32x4 aG[2], aU[2];        // acc [mf]
#pragma unroll
        for (int mf = 0; mf < 2; ++mf) {
            aG[mf] = (f32x4){0.f, 0.f, 0.f, 0.f};
            aU[mf] = (f32x4){0.f, 0.f, 0.f, 0.f};
        }
        // ---- kh = 0 : compute from sbuf0, stage kh1 -> sbuf1 ----
        stage_g<128, 16>(cbase, 256, 128, sbuf1, t);
#pragma unroll
        for (int kt = 0; kt < 4; ++kt) {
            int g = kt * 4 + kq;
            int gpg = (g & 8) | ((g ^ rowG) & 7);
            int gpu = (g & 8) | ((g ^ rowU) & 7);
            bf16x8 fG = *(const bf16x8*)&sbuf0[rowG * 128 + gpg * 8];
            bf16x8 fU = *(const bf16x8*)&sbuf0[rowU * 128 + gpu * 8];
#pragma unroll
            for (int mf = 0; mf < 2; ++mf) {
                aG[mf] = __builtin_amdgcn_mfma_f32_16x16x32_bf16(fG, P[mf][kt], aG[mf], 0, 0, 0);
                aU[mf] = __builtin_amdgcn_mfma_f32_16x16x32_bf16(fU, P[mf][kt], aU[mf], 0, 0, 0);
            }
        }
        __syncthreads();
        // ---- kh = 1 : compute from sbuf1, stage next chunk kh0 -> sbuf0 ----
        if (c < 7)
            stage_g<128, 16>(cbase + 128 * 256, 256, 0, sbuf0, t);
#pragma unroll
        for (int kt = 0; kt < 4; ++kt) {
            int g = kt * 4 + kq;
            int gpg = (g & 8) | ((g ^ rowG) & 7);
            int gpu = (g & 8) | ((g ^ rowU) & 7);
            bf16x8 fG = *(const bf16x8*)&sbuf1[rowG * 128 + gpg * 8];
            bf16x8 fU = *(const bf16x8*)&sbuf1[rowU * 128 + gpu * 8];
#pragma unroll
            for (int mf = 0; mf < 2; ++mf) {
                aG[mf] = __builtin_amdgcn_mfma_f32_16x16x32_bf16(fG, P[mf][4 + kt], aG[mf], 0, 0, 0);
                aU[mf] = __builtin_amdgcn_mfma_f32_16x16x32_bf16(fU, P[mf][4 + kt], aU[mf], 0, 0, 0);
            }
        }
        // hact write: h = c*64 + hg*16 + kq*4 + r, m = mg*32 + mf*16 + l16
#pragma unroll
        for (int mf = 0; mf < 2; ++mf) {
            float hv[4];
#pragma unroll
            for (int r = 0; r < 4; ++r) {
                float g = aG[mf][r];
                float u = aU[mf][r];
                hv[r] = g * (1.0f / (1.0f + __expf(-g))) * u;
            }
            int m = mg * 32 + mf * 16 + l16;
            int gr = c * 8 + hg * 2 + (kq >> 1);
            int gp = (gr & ~7) | ((gr ^ m) & 7);
            int sidx = m * 512 + gp * 8 + (kq & 1) * 4;
            *(unsigned int*)&hact[sidx]     = pack2(hv[0], hv[1]);
            *(unsigned int*)&hact[sidx + 2] = pack2(hv[2], hv[3]);
        }
        __syncthreads();
    }

    // ---- phase B roles ----
    int dg = w >> 1;               // 0..3  (64 d-cols each)
    int ks = w & 1;                // k-parity (32-h of every 64-h chunk)

    f32x4 accB[4][4];
#pragma unroll
    for (int mf = 0; mf < 4; ++mf)
#pragma unroll
        for (int df = 0; df < 4; ++df) accB[mf][df] = (f32x4){0.f, 0.f, 0.f, 0.f};

    stage_g<256, 8>(w2H, 512, 0, sbuf0, t);
    __syncthreads();

#pragma unroll 1
    for (int c = 0; c < 8; ++c) {
        short* cur = (c & 1) ? sbuf1 : sbuf0;
        short* nxt = (c & 1) ? sbuf0 : sbuf1;
        if (c < 7) stage_g<256, 8>(w2H, 512, (c + 1) * 64, nxt, t);

        bf16x8 aH[4], bW[4];
#pragma unroll
        for (int mf = 0; mf < 4; ++mf) {
            int m = mf * 16 + l16;
            int gr = c * 8 + ks * 4 + kq;
            int gp = (gr & ~7) | ((gr ^ m) & 7);
            aH[mf] = *(const bf16x8*)&hact[m * 512 + gp * 8];
        }
#pragma unroll
        for (int df = 0; df < 4; ++df) {
            int d = dg * 64 + df * 16 + l16;
            int gp = ((ks * 4 + kq) ^ d) & 7;
            bW[df] = *(const bf16x8*)&cur[d * 64 + gp * 8];
        }
#pragma unroll
        for (int mf = 0; mf < 4; ++mf)
#pragma unroll
            for (int df = 0; df < 4; ++df)
                accB[mf][df] = __builtin_amdgcn_mfma_f32_16x16x32_bf16(
                    aH[mf], bW[df], accB[mf][df], 0, 0, 0);
        __syncthreads();
    }

    // ---- pair-reduce (ks=1 -> LDS) + residual + store (ks=0) ----
    if (ks == 1) {
#pragma unroll
        for (int mf = 0; mf < 4; ++mf)
#pragma unroll
            for (int df = 0; df < 4; ++df)
#pragma unroll
                for (int r = 0; r < 4; ++r) {
                    int m = mf * 16 + kq * 4 + r;
                    int dl = df * 16 + l16;
                    red[dg * 4096 + m * 64 + dl] = accB[mf][df][r];
                }
    }
    __syncthreads();
    if (ks == 0) {
#pragma unroll
        for (int mf = 0; mf < 4; ++mf)
#pragma unroll
            for (int df = 0; df < 4; ++df)
#pragma unroll
                for (int r = 0; r < 4; ++r) {
                    int m = mf * 16 + kq * 4 + r;
                    int dl = df * 16 + l16;
                    int d = dg * 64 + dl;
                    int row = mtB + m;
                    float v = accB[mf][df][r] + red[dg * 4096 + m * 64 + dl];
                    v += bf2f(pb[((size_t)head * B_ + row) * D_ + d]);
                    out[(size_t)row * (N_ * D_) + head * D_ + d] = v;
                }
    }
}

// ---------------------------------------------------------------------------
extern "C" void kernel_launch(void* const* d_in, const int* in_sizes, int n_in,
                              void* d_out, int out_size, void* d_ws, size_t ws_size,
                              hipStream_t stream) {
    const float* x   = (const float*)d_in[0];
    const float* n1w = (const float*)d_in[1];
    const float* n2w = (const float*)d_in[2];
    const float* w1  = (const float*)d_in[3];
    const float* w3  = (const float*)d_in[4];
    const float* w2  = (const float*)d_in[5];
    float* out = (float*)d_out;

    char* ws = (char*)d_ws;
    // ws layout (total ~140 MiB):
    short* wgu = (short*)(ws);                        //  8 MiB (interleaved G/U)
    short* w2t = (short*)(ws + (8ull  << 20));        //  4 MiB
    short* pn  = (short*)(ws + (12ull << 20));        // 64 MiB (bf16, head-major)
    short* pb  = (short*)(ws + (76ull << 20));        // 64 MiB (bf16, head-major)

    (void)hipFuncSetAttribute((const void*)k_ffn,
                              hipFuncAttributeMaxDynamicSharedMemorySize, 131072);

    k_prep<<<(N_ * D_ * H_) / 256, 256, 0, stream>>>(w1, w3, w2, wgu, w2t);
    k_mix<<<B_, 256, 0, stream>>>(x, n1w, n2w, pb, pn);
    k_ffn<<<N_ * (B_ / 64), 512, 131072, stream>>>(pn, wgu, w2t, pb, out);
}

// Round 8
// 296.688 us; speedup vs baseline: 1.0709x; 1.0709x over previous
//
#include <hip/hip_runtime.h>
#include <hip/hip_bf16.h>

// Problem constants: x (B,N,D) fp32; per-head SwiGLU FFN H=512.
#define B_ 8192
#define N_ 16
#define D_ 256
#define H_ 512

using bf16x8 = __attribute__((ext_vector_type(8))) short;
using f32x4  = __attribute__((ext_vector_type(4))) float;

__device__ __forceinline__ void gload_lds16(const void* g, void* l) {
    __builtin_amdgcn_global_load_lds(
        (const __attribute__((address_space(1))) void*)g,
        (__attribute__((address_space(3))) void*)l, 16, 0, 0);
}

__device__ __forceinline__ short f2bf(float f) {
    unsigned int u = __float_as_uint(f);
    u += 0x7fffu + ((u >> 16) & 1u);   // round-to-nearest-even
    return (short)(u >> 16);
}

__device__ __forceinline__ float bf2f(short s) {
    return __uint_as_float(((unsigned int)(unsigned short)s) << 16);
}

__device__ __forceinline__ f32x4 mfma(bf16x8 a, bf16x8 b, f32x4 c) {
    return __builtin_amdgcn_mfma_f32_16x16x32_bf16(a, b, c, 0, 0, 0);
}

// ---------------------------------------------------------------------------
// Staging: operand panel 256 rows x 64 cols bf16 (one BK=64 K-tile).
// Linear LDS dest (gload_lds requirement) + inverse-swizzled global source:
// LDS granule slot g of row r holds global granule (g ^ r) & 7. 512 threads.
// ---------------------------------------------------------------------------
__device__ __forceinline__ void stage_ab(const short* __restrict__ Ag, int sA,
                                         const short* __restrict__ Bg, int sB,
                                         int k0, short* Al, short* Bl, int t) {
#pragma unroll
    for (int rnd = 0; rnd < 4; ++rnd) {
        int flat = rnd * 512 + t;
        int row = flat >> 3, g = flat & 7;
        int sg = (g ^ row) & 7;
        gload_lds16(Ag + (size_t)row * sA + k0 + sg * 8, Al + flat * 8);
    }
#pragma unroll
    for (int rnd = 0; rnd < 4; ++rnd) {
        int flat = rnd * 512 + t;
        int row = flat >> 3, g = flat & 7;
        int sg = (g ^ row) & 7;
        gload_lds16(Bg + (size_t)row * sB + k0 + sg * 8, Bl + flat * 8);
    }
}

// Swizzled fragment read: slot [256 rows][64 cols]; global granule g of row r
// lives in slot (g ^ r) & 7.
__device__ __forceinline__ bf16x8 rdfrag(const short* base, int row, int g) {
    int gp = (g ^ row) & 7;
    return *(const bf16x8*)&base[(row << 6) + (gp << 3)];
}

// ---------------------------------------------------------------------------
// Safe 2-phase GEMM core: 256x256 tile, BK=64, NT K-tiles, 8 waves (2M x 4N),
// per-wave 128(M) x 64(N), acc[8][4]. One __syncthreads per K-tile:
//   { issue stage(kt+1) -> other slot; ds_read + 64 MFMA from slot kt;
//     __syncthreads }  (barrier drains vmcnt/lgkmcnt -> slot kt+1 valid,
//     and all reads of slot kt are done before its next overwrite).
// LDS 128 KiB: A slots at shorts [0,16K),[16K,32K); B at [32K,48K),[48K,64K).
// ---------------------------------------------------------------------------
template<int NT>
__device__ __forceinline__ void gemm_core(const short* __restrict__ Ag, int sA,
                                          const short* __restrict__ Bg, int sB,
                                          short* lds, f32x4 (&acc)[8][4],
                                          int t, int rowA0, int rowB0) {
    int lane = t & 63;
    int l16 = lane & 15, kq = lane >> 4;

    stage_ab(Ag, sA, Bg, sB, 0, lds, lds + 32768, t);
    __syncthreads();

#pragma unroll 1
    for (int kt = 0; kt < NT; ++kt) {
        short* Asl = lds + (kt & 1) * 16384;
        short* Bsl = lds + 32768 + (kt & 1) * 16384;
        if (kt + 1 < NT)
            stage_ab(Ag, sA, Bg, sB, (kt + 1) * 64,
                     lds + ((kt + 1) & 1) * 16384,
                     lds + 32768 + ((kt + 1) & 1) * 16384, t);

        bf16x8 aF[4], bF[4];
        // ---- k-half 0 ----
#pragma unroll
        for (int j = 0; j < 4; ++j)
            bF[j] = rdfrag(Bsl, rowB0 + j * 16 + l16, kq);
#pragma unroll
        for (int i = 0; i < 4; ++i)
            aF[i] = rdfrag(Asl, rowA0 + i * 16 + l16, kq);
#pragma unroll
        for (int i = 0; i < 4; ++i)
#pragma unroll
            for (int j = 0; j < 4; ++j)
                acc[i][j] = mfma(aF[i], bF[j], acc[i][j]);
#pragma unroll
        for (int i = 0; i < 4; ++i)
            aF[i] = rdfrag(Asl, rowA0 + 64 + i * 16 + l16, kq);
#pragma unroll
        for (int i = 0; i < 4; ++i)
#pragma unroll
            for (int j = 0; j < 4; ++j)
                acc[4 + i][j] = mfma(aF[i], bF[j], acc[4 + i][j]);
        // ---- k-half 1 ----
#pragma unroll
        for (int j = 0; j < 4; ++j)
            bF[j] = rdfrag(Bsl, rowB0 + j * 16 + l16, 4 + kq);
#pragma unroll
        for (int i = 0; i < 4; ++i)
            aF[i] = rdfrag(Asl, rowA0 + i * 16 + l16, 4 + kq);
#pragma unroll
        for (int i = 0; i < 4; ++i)
#pragma unroll
            for (int j = 0; j < 4; ++j)
                acc[i][j] = mfma(aF[i], bF[j], acc[i][j]);
#pragma unroll
        for (int i = 0; i < 4; ++i)
            aF[i] = rdfrag(Asl, rowA0 + 64 + i * 16 + l16, 4 + kq);
#pragma unroll
        for (int i = 0; i < 4; ++i)
#pragma unroll
            for (int j = 0; j < 4; ++j)
                acc[4 + i][j] = mfma(aF[i], bF[j], acc[4 + i][j]);

        __syncthreads();
    }
}

// ---------------------------------------------------------------------------
// k_prep: fp32 weights -> bf16.
//   wgu: [n][1024 rows][256] where row ri = (h>>4)*32 + which*16 + (h&15),
//        which 0=W1(gate), 1=W3(up)  -> G/U rows adjacent at 16-granularity.
//   w2t: [n][d][h]  (B^T of (H,D))
// ---------------------------------------------------------------------------
__global__ __launch_bounds__(256) void k_prep(const float* __restrict__ w1,
                                              const float* __restrict__ w3,
                                              const float* __restrict__ w2,
                                              short* __restrict__ wgu,
                                              short* __restrict__ w2t) {
    int o = blockIdx.x * 256 + threadIdx.x;      // 0 .. N*D*H-1 (2M)
    int n = o >> 17;                              // / (D*H = 131072)
    int r = o & 131071;
    int h = r >> 8, d = r & 255;
    size_t base = ((size_t)n * 1024 + (h >> 4) * 32 + (h & 15)) * 256 + d;
    wgu[base]            = f2bf(w1[(size_t)n * 131072 + (size_t)d * 512 + h]);
    wgu[base + 16 * 256] = f2bf(w3[(size_t)n * 131072 + (size_t)d * 512 + h]);
    int d2 = r >> 9, h2 = r & 511;                // [n][d][h] out layout
    w2t[o] = f2bf(w2[(size_t)n * 131072 + (size_t)h2 * 256 + d2]);
}

// ---------------------------------------------------------------------------
// k_mix: per-b block. rmsnorm1 -> head_mixing -> +x -> rmsnorm2.
// Writes pb (bf16) and pn (bf16), both head-major [head][b][d].
// ---------------------------------------------------------------------------
__global__ __launch_bounds__(256) void k_mix(const float* __restrict__ x,
                                             const float* __restrict__ n1w,
                                             const float* __restrict__ n2w,
                                             short* __restrict__ pb_ws,
                                             short* __restrict__ pn_ws) {
    __shared__ float xs[N_ * D_];
    __shared__ float ps[N_ * D_];
    __shared__ float inv1[N_];
    __shared__ float inv2[N_];
    int b = blockIdx.x;
    int t = threadIdx.x;

    const float4* xb4 = (const float4*)(x + (size_t)b * (N_ * D_));
    float4* xs4 = (float4*)xs;
#pragma unroll
    for (int i = 0; i < 4; ++i) xs4[t + i * 256] = xb4[t + i * 256];
    __syncthreads();

    int hh = t >> 4, sub = t & 15;
    float s = 0.f;
#pragma unroll
    for (int j = 0; j < 16; ++j) { float v = xs[hh * 256 + sub * 16 + j]; s += v * v; }
    s += __shfl_xor(s, 1); s += __shfl_xor(s, 2);
    s += __shfl_xor(s, 4); s += __shfl_xor(s, 8);
    if (sub == 0) inv1[hh] = rsqrtf(s * (1.0f / 256.0f) + 1e-6f);
    __syncthreads();

    {
        int n = t >> 4, j = t & 15;               // d = t
#pragma unroll 1
        for (int m = 0; m < 16; ++m) {
            float v = xs[n * 256 + m * 16 + j] * inv1[n] * n1w[m * 16 + j]
                    + xs[m * 256 + t];
            ps[m * 256 + t] = v;
        }
    }
    __syncthreads();

    float s2 = 0.f;
#pragma unroll
    for (int j = 0; j < 16; ++j) { float v = ps[hh * 256 + sub * 16 + j]; s2 += v * v; }
    s2 += __shfl_xor(s2, 1); s2 += __shfl_xor(s2, 2);
    s2 += __shfl_xor(s2, 4); s2 += __shfl_xor(s2, 8);
    if (sub == 0) inv2[hh] = rsqrtf(s2 * (1.0f / 256.0f) + 1e-6f);
    __syncthreads();

#pragma unroll 1
    for (int m = 0; m < 16; ++m) {
        float v = ps[m * 256 + t];
        size_t off = ((size_t)m * B_ + b) * D_ + t;
        pb_ws[off] = f2bf(v);
        pn_ws[off] = f2bf(v * inv2[m] * n2w[t]);
    }
}

// ---------------------------------------------------------------------------
// k_gu: [G|U] = Pn @ Wgu^T per head (M=8192, N=1024 interleaved, K=256),
// silu(G)*U epilogue -> hact [head][m][h] bf16.
// ---------------------------------------------------------------------------
__global__ __launch_bounds__(512, 2) void k_gu(const short* __restrict__ pn,
                                               const short* __restrict__ wgu,
                                               short* __restrict__ hact) {
    extern __shared__ char smem[];
    short* lds = (short*)smem;

    // XCD-aware bijective swizzle: 2048 blocks, 256 per XCD chunk.
    int bid = blockIdx.x;
    int bx = (bid & 7) * 256 + (bid >> 3);
    int head = bx >> 7;
    int mt = (bx >> 2) & 31;
    int nt = bx & 3;

    int t = threadIdx.x;
    int w = t >> 6, lane = t & 63;
    int l16 = lane & 15, kq = lane >> 4;
    int wm = w >> 2, wn = w & 3;

    f32x4 acc[8][4];
#pragma unroll
    for (int i = 0; i < 8; ++i)
#pragma unroll
        for (int j = 0; j < 4; ++j) acc[i][j] = (f32x4){0.f, 0.f, 0.f, 0.f};

    const short* Ag = pn  + ((size_t)head * B_ + (size_t)mt * 256) * D_;
    const short* Bg = wgu + ((size_t)head * 1024 + (size_t)nt * 256) * D_;

    gemm_core<4>(Ag, D_, Bg, D_, lds, acc, t, wm * 128, wn * 64);

    // epilogue: nf pairs (0,1) and (2,3) are (G,U) of the same 16 h's.
    size_t hb = (size_t)head * B_ * H_;
#pragma unroll
    for (int mf = 0; mf < 8; ++mf) {
        int m = mt * 256 + wm * 128 + mf * 16 + kq * 4;
#pragma unroll
        for (int p = 0; p < 2; ++p) {
            int h = (nt * 8 + wn * 2 + p) * 16 + l16;
#pragma unroll
            for (int r = 0; r < 4; ++r) {
                float g = acc[mf][2 * p][r];
                float u = acc[mf][2 * p + 1][r];
                float hv = g * (1.0f / (1.0f + __expf(-g))) * u;
                hact[hb + (size_t)(m + r) * H_ + h] = f2bf(hv);
            }
        }
    }
}

// ---------------------------------------------------------------------------
// k_dn: Q = Hact @ W2 per head (M=8192, N=256, K=512) + pb -> out (B,N,D).
// ---------------------------------------------------------------------------
__global__ __launch_bounds__(512, 2) void k_dn(const short* __restrict__ hact,
                                               const short* __restrict__ w2t,
                                               const short* __restrict__ pb,
                                               float* __restrict__ out) {
    extern __shared__ char smem[];
    short* lds = (short*)smem;

    // XCD-aware bijective swizzle: 512 blocks, 64 per XCD chunk.
    int bid = blockIdx.x;
    int bx = (bid & 7) * 64 + (bid >> 3);
    int head = bx >> 5;
    int mt = bx & 31;

    int t = threadIdx.x;
    int w = t >> 6, lane = t & 63;
    int l16 = lane & 15, kq = lane >> 4;
    int wm = w >> 2, wn = w & 3;

    f32x4 acc[8][4];
#pragma unroll
    for (int i = 0; i < 8; ++i)
#pragma unroll
        for (int j = 0; j < 4; ++j) acc[i][j] = (f32x4){0.f, 0.f, 0.f, 0.f};

    const short* Ag = hact + ((size_t)head * B_ + (size_t)mt * 256) * H_;
    const short* Bg = w2t  + (size_t)head * D_ * H_;

    gemm_core<8>(Ag, H_, Bg, H_, lds, acc, t, wm * 128, wn * 64);

#pragma unroll
    for (int mf = 0; mf < 8; ++mf) {
        int m = mt * 256 + wm * 128 + mf * 16 + kq * 4;
#pragma unroll
        for (int nf = 0; nf < 4; ++nf) {
            int d = wn * 64 + nf * 16 + l16;
#pragma unroll
            for (int r = 0; r < 4; ++r) {
                float v = acc[mf][nf][r]
                        + bf2f(pb[((size_t)head * B_ + m + r) * D_ + d]);
                out[(size_t)(m + r) * (N_ * D_) + head * D_ + d] = v;
            }
        }
    }
}

// ---------------------------------------------------------------------------
extern "C" void kernel_launch(void* const* d_in, const int* in_sizes, int n_in,
                              void* d_out, int out_size, void* d_ws, size_t ws_size,
                              hipStream_t stream) {
    const float* x   = (const float*)d_in[0];
    const float* n1w = (const float*)d_in[1];
    const float* n2w = (const float*)d_in[2];
    const float* w1  = (const float*)d_in[3];
    const float* w3  = (const float*)d_in[4];
    const float* w2  = (const float*)d_in[5];
    float* out = (float*)d_out;

    char* ws = (char*)d_ws;
    // ws layout (total ~268 MiB):
    short* wgu  = (short*)(ws);                       //  8 MiB (interleaved G/U)
    short* w2t  = (short*)(ws + (8ull   << 20));      //  4 MiB
    short* pn   = (short*)(ws + (12ull  << 20));      // 64 MiB (bf16, head-major)
    short* pb   = (short*)(ws + (76ull  << 20));      // 64 MiB (bf16, head-major)
    short* hact = (short*)(ws + (140ull << 20));      // 128 MiB (bf16, head-major)

    (void)hipFuncSetAttribute((const void*)k_gu,
                              hipFuncAttributeMaxDynamicSharedMemorySize, 131072);
    (void)hipFuncSetAttribute((const void*)k_dn,
                              hipFuncAttributeMaxDynamicSharedMemorySize, 131072);

    k_prep<<<(N_ * D_ * H_) / 256, 256, 0, stream>>>(w1, w3, w2, wgu, w2t);
    k_mix<<<B_, 256, 0, stream>>>(x, n1w, n2w, pb, pn);
    k_gu<<<N_ * (B_ / 256) * 4, 512, 131072, stream>>>(pn, wgu, hact);
    k_dn<<<N_ * (B_ / 256), 512, 131072, stream>>>(hact, w2t, pb, out);
}

// Round 9
// 296.541 us; speedup vs baseline: 1.0714x; 1.0005x over previous
//
#include <hip/hip_runtime.h>
#include <hip/hip_bf16.h>

// Problem constants: x (B,N,D) fp32; per-head SwiGLU FFN H=512.
#define B_ 8192
#define N_ 16
#define D_ 256
#define H_ 512

using bf16x8 = __attribute__((ext_vector_type(8))) short;
using f32x4  = __attribute__((ext_vector_type(4))) float;

__device__ __forceinline__ void gload_lds16(const void* g, void* l) {
    __builtin_amdgcn_global_load_lds(
        (const __attribute__((address_space(1))) void*)g,
        (__attribute__((address_space(3))) void*)l, 16, 0, 0);
}

__device__ __forceinline__ short f2bf(float f) {
    unsigned int u = __float_as_uint(f);
    u += 0x7fffu + ((u >> 16) & 1u);   // round-to-nearest-even
    return (short)(u >> 16);
}

__device__ __forceinline__ float bf2f(short s) {
    return __uint_as_float(((unsigned int)(unsigned short)s) << 16);
}

__device__ __forceinline__ unsigned int pack2(float lo, float hi) {
    return (unsigned int)(unsigned short)f2bf(lo)
         | ((unsigned int)(unsigned short)f2bf(hi) << 16);
}

__device__ __forceinline__ f32x4 mfma(bf16x8 a, bf16x8 b, f32x4 c) {
    return __builtin_amdgcn_mfma_f32_16x16x32_bf16(a, b, c, 0, 0, 0);
}

// Swizzled fragment read for [128 rows][32 cols] panels (4 granule slots):
// global granule g of row r lives in slot (g ^ r) & 3.
__device__ __forceinline__ bf16x8 rd32(const short* base, int row, int g) {
    int gp = (g ^ row) & 3;
    return *(const bf16x8*)&base[(row << 5) + (gp << 3)];
}

// ---------------------------------------------------------------------------
// m97-structure GEMM core: 128x128 tile, BK=32, NT K-tiles, 4 waves (2M x 2N),
// per-wave 64x64, acc[4][4]. Single-buffered 16 KiB LDS, 2 __syncthreads per
// K-step (R8-verified semantics: sync drains vmcnt -> tile valid; second sync
// protects WAR on the re-staged buffer). Relies on 4+ blocks/CU for overlap.
// Staging: linear LDS dest + inverse-XOR global source (both-sides swizzle).
// ---------------------------------------------------------------------------
template<int NT>
__device__ __forceinline__ void gemm97(const short* __restrict__ Ag, int sA,
                                       const short* __restrict__ Bg, int sB,
                                       short* As, short* Bs,
                                       f32x4 (&acc)[4][4],
                                       int t, int rowA0, int rowB0) {
    int lane = t & 63;
    int l16 = lane & 15, kq = lane >> 4;

#pragma unroll 1
    for (int kt = 0; kt < NT; ++kt) {
        int k0 = kt * 32;
#pragma unroll
        for (int rnd = 0; rnd < 2; ++rnd) {
            int flat = rnd * 256 + t;
            int row = flat >> 2, g = flat & 3;
            int sg = (g ^ row) & 3;
            gload_lds16(Ag + (size_t)row * sA + k0 + sg * 8, As + flat * 8);
        }
#pragma unroll
        for (int rnd = 0; rnd < 2; ++rnd) {
            int flat = rnd * 256 + t;
            int row = flat >> 2, g = flat & 3;
            int sg = (g ^ row) & 3;
            gload_lds16(Bg + (size_t)row * sB + k0 + sg * 8, Bs + flat * 8);
        }
        __syncthreads();

        bf16x8 aF[4], bF[4];
#pragma unroll
        for (int j = 0; j < 4; ++j)
            bF[j] = rd32(Bs, rowB0 + j * 16 + l16, kq);
#pragma unroll
        for (int i = 0; i < 4; ++i)
            aF[i] = rd32(As, rowA0 + i * 16 + l16, kq);
#pragma unroll
        for (int i = 0; i < 4; ++i)
#pragma unroll
            for (int j = 0; j < 4; ++j)
                acc[i][j] = mfma(aF[i], bF[j], acc[i][j]);
        __syncthreads();
    }
}

// ---------------------------------------------------------------------------
// k_prep: fp32 weights -> bf16.
//   wgu: [n][1024 rows][256] where row ri = (h>>4)*32 + which*16 + (h&15),
//        which 0=W1(gate), 1=W3(up)  -> G/U rows adjacent at 16-granularity.
//   w2t: [n][d][h]  (B^T of (H,D))
// ---------------------------------------------------------------------------
__global__ __launch_bounds__(256) void k_prep(const float* __restrict__ w1,
                                              const float* __restrict__ w3,
                                              const float* __restrict__ w2,
                                              short* __restrict__ wgu,
                                              short* __restrict__ w2t) {
    int o = blockIdx.x * 256 + threadIdx.x;      // 0 .. N*D*H-1 (2M)
    int n = o >> 17;                              // / (D*H = 131072)
    int r = o & 131071;
    int h = r >> 8, d = r & 255;
    size_t base = ((size_t)n * 1024 + (h >> 4) * 32 + (h & 15)) * 256 + d;
    wgu[base]            = f2bf(w1[(size_t)n * 131072 + (size_t)d * 512 + h]);
    wgu[base + 16 * 256] = f2bf(w3[(size_t)n * 131072 + (size_t)d * 512 + h]);
    int d2 = r >> 9, h2 = r & 511;                // [n][d][h] out layout
    w2t[o] = f2bf(w2[(size_t)n * 131072 + (size_t)h2 * 256 + d2]);
}

// ---------------------------------------------------------------------------
// k_mix v2: per-b block. rmsnorm1 -> head_mixing -> +x -> rmsnorm2.
// Wave-parallel float4 row sums (64 lanes, shfl_xor reduce) + packed bf16x2
// stores. Writes pb (bf16) and pn (bf16), head-major [head][b][d].
// ---------------------------------------------------------------------------
__global__ __launch_bounds__(256) void k_mix(const float* __restrict__ x,
                                             const float* __restrict__ n1w,
                                             const float* __restrict__ n2w,
                                             unsigned int* __restrict__ pb_u,
                                             unsigned int* __restrict__ pn_u) {
    __shared__ __align__(16) float xs[N_ * D_];
    __shared__ __align__(16) float ps[N_ * D_];
    __shared__ float inv1[N_];
    __shared__ float inv2[N_];
    int b = blockIdx.x;
    int t = threadIdx.x;
    int w = t >> 6, lane = t & 63;

    const float4* xb4 = (const float4*)(x + (size_t)b * (N_ * D_));
    float4* xs4 = (float4*)xs;
    float4* ps4 = (float4*)ps;
#pragma unroll
    for (int i = 0; i < 4; ++i) xs4[t + i * 256] = xb4[t + i * 256];
    __syncthreads();

    // pass 1: row sums of x^2, one row per (wave, q), all 64 lanes active
#pragma unroll
    for (int q = 0; q < 4; ++q) {
        int row = w * 4 + q;
        float4 v = xs4[row * 64 + lane];
        float s = v.x * v.x + v.y * v.y + v.z * v.z + v.w * v.w;
        s += __shfl_xor(s, 1);  s += __shfl_xor(s, 2);
        s += __shfl_xor(s, 4);  s += __shfl_xor(s, 8);
        s += __shfl_xor(s, 16); s += __shfl_xor(s, 32);
        if (lane == 0) inv1[row] = rsqrtf(s * (1.0f / 256.0f) + 1e-6f);
    }
    __syncthreads();

    // head-mix + residual: thread owns column d = t
    {
        int n = t >> 4, j = t & 15;
        float i1 = inv1[n];
#pragma unroll 1
        for (int m = 0; m < 16; ++m) {
            float v = xs[n * 256 + m * 16 + j] * i1 * n1w[m * 16 + j]
                    + xs[m * 256 + t];
            ps[m * 256 + t] = v;
        }
    }
    __syncthreads();

    // pass 2: row sums of p^2
#pragma unroll
    for (int q = 0; q < 4; ++q) {
        int row = w * 4 + q;
        float4 v = ps4[row * 64 + lane];
        float s = v.x * v.x + v.y * v.y + v.z * v.z + v.w * v.w;
        s += __shfl_xor(s, 1);  s += __shfl_xor(s, 2);
        s += __shfl_xor(s, 4);  s += __shfl_xor(s, 8);
        s += __shfl_xor(s, 16); s += __shfl_xor(s, 32);
        if (lane == 0) inv2[row] = rsqrtf(s * (1.0f / 256.0f) + 1e-6f);
    }
    __syncthreads();

    // packed store: thread handles d-pair (2*dh, 2*dh+1) for 8 rows
    int dh = t & 127, mh = t >> 7;
    float wA = n2w[2 * dh], wB = n2w[2 * dh + 1];
#pragma unroll
    for (int i = 0; i < 8; ++i) {
        int m = mh * 8 + i;
        float2 f = *(const float2*)&ps[m * 256 + 2 * dh];
        float iv = inv2[m];
        size_t off = ((size_t)m * B_ + b) * (D_ / 2) + dh;
        pb_u[off] = pack2(f.x, f.y);
        pn_u[off] = pack2(f.x * iv * wA, f.y * iv * wB);
    }
}

// ---------------------------------------------------------------------------
// k_gu: [G|U] = Pn @ Wgu^T per head (M=8192/head, N=1024 interleaved, K=256),
// silu(G)*U epilogue -> hact [head][m][h] bf16. 128x128 tile.
// ---------------------------------------------------------------------------
__global__ __launch_bounds__(256, 4) void k_gu(const short* __restrict__ pn,
                                               const short* __restrict__ wgu,
                                               short* __restrict__ hact) {
    __shared__ __align__(16) short As[128 * 32];
    __shared__ __align__(16) short Bs[128 * 32];

    // XCD-aware bijective swizzle: 8192 blocks, 1024 per XCD chunk.
    int bid = blockIdx.x;
    int bx = (bid & 7) * 1024 + (bid >> 3);
    int head = bx >> 9;
    int mt = (bx >> 3) & 63;      // nt fastest -> A-tile L2 reuse
    int nt = bx & 7;

    int t = threadIdx.x;
    int w = t >> 6, lane = t & 63;
    int l16 = lane & 15, kq = lane >> 4;
    int wm = w >> 1, wn = w & 1;

    f32x4 acc[4][4];
#pragma unroll
    for (int i = 0; i < 4; ++i)
#pragma unroll
        for (int j = 0; j < 4; ++j) acc[i][j] = (f32x4){0.f, 0.f, 0.f, 0.f};

    const short* Ag = pn  + ((size_t)head * B_ + (size_t)mt * 128) * D_;
    const short* Bg = wgu + ((size_t)head * 1024 + (size_t)nt * 128) * D_;

    gemm97<8>(Ag, D_, Bg, D_, As, Bs, acc, t, wm * 64, wn * 64);

    // epilogue: B-row pairs (nf=0,1) and (2,3) are (G,U) of the same 16 h's.
    size_t hb = (size_t)head * B_ * H_;
#pragma unroll
    for (int mf = 0; mf < 4; ++mf) {
        int m = mt * 128 + wm * 64 + mf * 16 + kq * 4;
#pragma unroll
        for (int p = 0; p < 2; ++p) {
            int h = nt * 64 + (wn * 2 + p) * 16 + l16;
#pragma unroll
            for (int r = 0; r < 4; ++r) {
                float g = acc[mf][2 * p][r];
                float u = acc[mf][2 * p + 1][r];
                float hv = g * (1.0f / (1.0f + __expf(-g))) * u;
                hact[hb + (size_t)(m + r) * H_ + h] = f2bf(hv);
            }
        }
    }
}

// ---------------------------------------------------------------------------
// k_dn: Q = Hact @ W2 per head (M=8192/head, N=256, K=512) + pb -> (B,N,D).
// 128x128 tile.
// ---------------------------------------------------------------------------
__global__ __launch_bounds__(256, 4) void k_dn(const short* __restrict__ hact,
                                               const short* __restrict__ w2t,
                                               const short* __restrict__ pb,
                                               float* __restrict__ out) {
    __shared__ __align__(16) short As[128 * 32];
    __shared__ __align__(16) short Bs[128 * 32];

    // XCD-aware bijective swizzle: 2048 blocks, 256 per XCD chunk.
    int bid = blockIdx.x;
    int bx = (bid & 7) * 256 + (bid >> 3);
    int head = bx >> 7;
    int mt = (bx >> 1) & 63;      // nt fastest -> A-tile L2 reuse
    int nt = bx & 1;

    int t = threadIdx.x;
    int w = t >> 6, lane = t & 63;
    int l16 = lane & 15, kq = lane >> 4;
    int wm = w >> 1, wn = w & 1;

    f32x4 acc[4][4];
#pragma unroll
    for (int i = 0; i < 4; ++i)
#pragma unroll
        for (int j = 0; j < 4; ++j) acc[i][j] = (f32x4){0.f, 0.f, 0.f, 0.f};

    const short* Ag = hact + ((size_t)head * B_ + (size_t)mt * 128) * H_;
    const short* Bg = w2t  + ((size_t)head * D_ + (size_t)nt * 128) * H_;

    gemm97<16>(Ag, H_, Bg, H_, As, Bs, acc, t, wm * 64, wn * 64);

#pragma unroll
    for (int mf = 0; mf < 4; ++mf) {
        int m = mt * 128 + wm * 64 + mf * 16 + kq * 4;
#pragma unroll
        for (int nf = 0; nf < 4; ++nf) {
            int d = nt * 128 + wn * 64 + nf * 16 + l16;
#pragma unroll
            for (int r = 0; r < 4; ++r) {
                float v = acc[mf][nf][r]
                        + bf2f(pb[((size_t)head * B_ + m + r) * D_ + d]);
                out[(size_t)(m + r) * (N_ * D_) + head * D_ + d] = v;
            }
        }
    }
}

// ---------------------------------------------------------------------------
extern "C" void kernel_launch(void* const* d_in, const int* in_sizes, int n_in,
                              void* d_out, int out_size, void* d_ws, size_t ws_size,
                              hipStream_t stream) {
    const float* x   = (const float*)d_in[0];
    const float* n1w = (const float*)d_in[1];
    const float* n2w = (const float*)d_in[2];
    const float* w1  = (const float*)d_in[3];
    const float* w3  = (const float*)d_in[4];
    const float* w2  = (const float*)d_in[5];
    float* out = (float*)d_out;

    char* ws = (char*)d_ws;
    // ws layout (total ~268 MiB):
    short* wgu  = (short*)(ws);                       //  8 MiB (interleaved G/U)
    short* w2t  = (short*)(ws + (8ull   << 20));      //  4 MiB
    short* pn   = (short*)(ws + (12ull  << 20));      // 64 MiB (bf16, head-major)
    short* pb   = (short*)(ws + (76ull  << 20));      // 64 MiB (bf16, head-major)
    short* hact = (short*)(ws + (140ull << 20));      // 128 MiB (bf16, head-major)

    k_prep<<<(N_ * D_ * H_) / 256, 256, 0, stream>>>(w1, w3, w2, wgu, w2t);
    k_mix<<<B_, 256, 0, stream>>>(x, n1w, n2w,
                                  (unsigned int*)pb, (unsigned int*)pn);
    k_gu<<<N_ * (B_ / 128) * (1024 / 128), 256, 0, stream>>>(pn, wgu, hact);
    k_dn<<<N_ * (B_ / 128) * (D_ / 128), 256, 0, stream>>>(hact, w2t, pb, out);
}

// Round 10
// 285.952 us; speedup vs baseline: 1.1111x; 1.0370x over previous
//
#include <hip/hip_runtime.h>
#include <hip/hip_bf16.h>

// Problem constants: x (B,N,D) fp32; per-head SwiGLU FFN H=512.
#define B_ 8192
#define N_ 16
#define D_ 256
#define H_ 512

using bf16x8 = __attribute__((ext_vector_type(8))) short;
using f32x4  = __attribute__((ext_vector_type(4))) float;

__device__ __forceinline__ void gload_lds16(const void* g, void* l) {
    __builtin_amdgcn_global_load_lds(
        (const __attribute__((address_space(1))) void*)g,
        (__attribute__((address_space(3))) void*)l, 16, 0, 0);
}

__device__ __forceinline__ short f2bf(float f) {
    unsigned int u = __float_as_uint(f);
    u += 0x7fffu + ((u >> 16) & 1u);   // round-to-nearest-even
    return (short)(u >> 16);
}

__device__ __forceinline__ float bf2f(short s) {
    return __uint_as_float(((unsigned int)(unsigned short)s) << 16);
}

__device__ __forceinline__ unsigned int pack2(float lo, float hi) {
    return (unsigned int)(unsigned short)f2bf(lo)
         | ((unsigned int)(unsigned short)f2bf(hi) << 16);
}

__device__ __forceinline__ f32x4 mfma(bf16x8 a, bf16x8 b, f32x4 c) {
    return __builtin_amdgcn_mfma_f32_16x16x32_bf16(a, b, c, 0, 0, 0);
}

// Swizzled fragment read for [128 rows][64 cols] panels (8 granule slots):
// global granule g of row r lives in slot (g ^ r) & 7.  A wave's 64 lanes
// spread across all 8 16B-slots -> conflict-free ds_read_b128 (R8: 0 confl).
__device__ __forceinline__ bf16x8 rd64(const short* base, int row, int g) {
    int gp = (g ^ row) & 7;
    return *(const bf16x8*)&base[(row << 6) + (gp << 3)];
}

// ---------------------------------------------------------------------------
// GEMM core: 128x128 tile, BK=64, NT K-tiles, 4 waves (2M x 2N), per-wave
// 64x64, acc[4][4]. Single-buffered 32 KiB LDS, 2 __syncthreads per K-step
// (R8/R9-verified semantics: first sync drains vmcnt -> staged tile valid;
// second sync protects WAR before re-staging). Inter-block overlap from
// 4-5 co-resident blocks/CU hides the barrier drain (m114).
// Staging: linear LDS dest + inverse-XOR global source (both-sides swizzle).
// ---------------------------------------------------------------------------
template<int NT>
__device__ __forceinline__ void gemmc(const short* __restrict__ Ag, int sA,
                                      const short* __restrict__ Bg, int sB,
                                      short* As, short* Bs,
                                      f32x4 (&acc)[4][4],
                                      int t, int rowA0, int rowB0) {
    int lane = t & 63;
    int l16 = lane & 15, kq = lane >> 4;

#pragma unroll 1
    for (int kt = 0; kt < NT; ++kt) {
        int k0 = kt * 64;
#pragma unroll
        for (int rnd = 0; rnd < 4; ++rnd) {
            int flat = rnd * 256 + t;
            int row = flat >> 3, g = flat & 7;
            int sg = (g ^ row) & 7;
            gload_lds16(Ag + (size_t)row * sA + k0 + sg * 8, As + flat * 8);
        }
#pragma unroll
        for (int rnd = 0; rnd < 4; ++rnd) {
            int flat = rnd * 256 + t;
            int row = flat >> 3, g = flat & 7;
            int sg = (g ^ row) & 7;
            gload_lds16(Bg + (size_t)row * sB + k0 + sg * 8, Bs + flat * 8);
        }
        __syncthreads();

#pragma unroll
        for (int kh = 0; kh < 2; ++kh) {
            int g = kh * 4 + kq;
            bf16x8 aF[4], bF[4];
#pragma unroll
            for (int j = 0; j < 4; ++j)
                bF[j] = rd64(Bs, rowB0 + j * 16 + l16, g);
#pragma unroll
            for (int i = 0; i < 4; ++i)
                aF[i] = rd64(As, rowA0 + i * 16 + l16, g);
#pragma unroll
            for (int i = 0; i < 4; ++i)
#pragma unroll
                for (int j = 0; j < 4; ++j)
                    acc[i][j] = mfma(aF[i], bF[j], acc[i][j]);
        }
        __syncthreads();
    }
}

// ---------------------------------------------------------------------------
// k_prep: fp32 weights -> bf16.
//   wgu: [n][1024 rows][256] where row ri = (h>>4)*32 + which*16 + (h&15),
//        which 0=W1(gate), 1=W3(up)  -> G/U rows adjacent at 16-granularity.
//   w2t: [n][d][h]  (B^T of (H,D))
// ---------------------------------------------------------------------------
__global__ __launch_bounds__(256) void k_prep(const float* __restrict__ w1,
                                              const float* __restrict__ w3,
                                              const float* __restrict__ w2,
                                              short* __restrict__ wgu,
                                              short* __restrict__ w2t) {
    int o = blockIdx.x * 256 + threadIdx.x;      // 0 .. N*D*H-1 (2M)
    int n = o >> 17;                              // / (D*H = 131072)
    int r = o & 131071;
    int h = r >> 8, d = r & 255;
    size_t base = ((size_t)n * 1024 + (h >> 4) * 32 + (h & 15)) * 256 + d;
    wgu[base]            = f2bf(w1[(size_t)n * 131072 + (size_t)d * 512 + h]);
    wgu[base + 16 * 256] = f2bf(w3[(size_t)n * 131072 + (size_t)d * 512 + h]);
    int d2 = r >> 9, h2 = r & 511;                // [n][d][h] out layout
    w2t[o] = f2bf(w2[(size_t)n * 131072 + (size_t)h2 * 256 + d2]);
}

// ---------------------------------------------------------------------------
// k_mix: per-b block. rmsnorm1 -> head_mixing -> +x -> rmsnorm2.
// Wave-parallel float4 row sums (64 lanes, shfl_xor reduce) + packed bf16x2
// stores. Writes pb (bf16) and pn (bf16), head-major [head][b][d].
// ---------------------------------------------------------------------------
__global__ __launch_bounds__(256) void k_mix(const float* __restrict__ x,
                                             const float* __restrict__ n1w,
                                             const float* __restrict__ n2w,
                                             unsigned int* __restrict__ pb_u,
                                             unsigned int* __restrict__ pn_u) {
    __shared__ __align__(16) float xs[N_ * D_];
    __shared__ __align__(16) float ps[N_ * D_];
    __shared__ float inv1[N_];
    __shared__ float inv2[N_];
    int b = blockIdx.x;
    int t = threadIdx.x;
    int w = t >> 6, lane = t & 63;

    const float4* xb4 = (const float4*)(x + (size_t)b * (N_ * D_));
    float4* xs4 = (float4*)xs;
    float4* ps4 = (float4*)ps;
#pragma unroll
    for (int i = 0; i < 4; ++i) xs4[t + i * 256] = xb4[t + i * 256];
    __syncthreads();

    // pass 1: row sums of x^2, one row per (wave, q), all 64 lanes active
#pragma unroll
    for (int q = 0; q < 4; ++q) {
        int row = w * 4 + q;
        float4 v = xs4[row * 64 + lane];
        float s = v.x * v.x + v.y * v.y + v.z * v.z + v.w * v.w;
        s += __shfl_xor(s, 1);  s += __shfl_xor(s, 2);
        s += __shfl_xor(s, 4);  s += __shfl_xor(s, 8);
        s += __shfl_xor(s, 16); s += __shfl_xor(s, 32);
        if (lane == 0) inv1[row] = rsqrtf(s * (1.0f / 256.0f) + 1e-6f);
    }
    __syncthreads();

    // head-mix + residual: thread owns column d = t
    {
        int n = t >> 4, j = t & 15;
        float i1 = inv1[n];
#pragma unroll 1
        for (int m = 0; m < 16; ++m) {
            float v = xs[n * 256 + m * 16 + j] * i1 * n1w[m * 16 + j]
                    + xs[m * 256 + t];
            ps[m * 256 + t] = v;
        }
    }
    __syncthreads();

    // pass 2: row sums of p^2
#pragma unroll
    for (int q = 0; q < 4; ++q) {
        int row = w * 4 + q;
        float4 v = ps4[row * 64 + lane];
        float s = v.x * v.x + v.y * v.y + v.z * v.z + v.w * v.w;
        s += __shfl_xor(s, 1);  s += __shfl_xor(s, 2);
        s += __shfl_xor(s, 4);  s += __shfl_xor(s, 8);
        s += __shfl_xor(s, 16); s += __shfl_xor(s, 32);
        if (lane == 0) inv2[row] = rsqrtf(s * (1.0f / 256.0f) + 1e-6f);
    }
    __syncthreads();

    // packed store: thread handles d-pair (2*dh, 2*dh+1) for 8 rows
    int dh = t & 127, mh = t >> 7;
    float wA = n2w[2 * dh], wB = n2w[2 * dh + 1];
#pragma unroll
    for (int i = 0; i < 8; ++i) {
        int m = mh * 8 + i;
        float2 f = *(const float2*)&ps[m * 256 + 2 * dh];
        float iv = inv2[m];
        size_t off = ((size_t)m * B_ + b) * (D_ / 2) + dh;
        pb_u[off] = pack2(f.x, f.y);
        pn_u[off] = pack2(f.x * iv * wA, f.y * iv * wB);
    }
}

// ---------------------------------------------------------------------------
// k_gu: [G|U] = Pn @ Wgu^T per head (M=8192/head, N=1024 interleaved, K=256),
// silu(G)*U epilogue -> hact [head][m][h] bf16. 128x128 tile, BK=64, NT=4.
// ---------------------------------------------------------------------------
__global__ __launch_bounds__(256, 4) void k_gu(const short* __restrict__ pn,
                                               const short* __restrict__ wgu,
                                               short* __restrict__ hact) {
    __shared__ __align__(16) short As[128 * 64];
    __shared__ __align__(16) short Bs[128 * 64];

    // XCD-aware bijective swizzle: 8192 blocks, 1024 per XCD chunk.
    int bid = blockIdx.x;
    int bx = (bid & 7) * 1024 + (bid >> 3);
    int head = bx >> 9;
    int mt = (bx >> 3) & 63;      // nt fastest -> A-tile L2 reuse
    int nt = bx & 7;

    int t = threadIdx.x;
    int w = t >> 6, lane = t & 63;
    int l16 = lane & 15, kq = lane >> 4;
    int wm = w >> 1, wn = w & 1;

    f32x4 acc[4][4];
#pragma unroll
    for (int i = 0; i < 4; ++i)
#pragma unroll
        for (int j = 0; j < 4; ++j) acc[i][j] = (f32x4){0.f, 0.f, 0.f, 0.f};

    const short* Ag = pn  + ((size_t)head * B_ + (size_t)mt * 128) * D_;
    const short* Bg = wgu + ((size_t)head * 1024 + (size_t)nt * 128) * D_;

    gemmc<4>(Ag, D_, Bg, D_, As, Bs, acc, t, wm * 64, wn * 64);

    // epilogue: B-row pairs (nf=0,1) and (2,3) are (G,U) of the same 16 h's.
    size_t hb = (size_t)head * B_ * H_;
#pragma unroll
    for (int mf = 0; mf < 4; ++mf) {
        int m = mt * 128 + wm * 64 + mf * 16 + kq * 4;
#pragma unroll
        for (int p = 0; p < 2; ++p) {
            int h = nt * 64 + (wn * 2 + p) * 16 + l16;
#pragma unroll
            for (int r = 0; r < 4; ++r) {
                float g = acc[mf][2 * p][r];
                float u = acc[mf][2 * p + 1][r];
                float hv = g * (1.0f / (1.0f + __expf(-g))) * u;
                hact[hb + (size_t)(m + r) * H_ + h] = f2bf(hv);
            }
        }
    }
}

// ---------------------------------------------------------------------------
// k_dn: Q = Hact @ W2 per head (M=8192/head, N=256, K=512) + pb -> (B,N,D).
// 128x128 tile, BK=64, NT=8.
// ---------------------------------------------------------------------------
__global__ __launch_bounds__(256, 4) void k_dn(const short* __restrict__ hact,
                                               const short* __restrict__ w2t,
                                               const short* __restrict__ pb,
                                               float* __restrict__ out) {
    __shared__ __align__(16) short As[128 * 64];
    __shared__ __align__(16) short Bs[128 * 64];

    // XCD-aware bijective swizzle: 2048 blocks, 256 per XCD chunk.
    int bid = blockIdx.x;
    int bx = (bid & 7) * 256 + (bid >> 3);
    int head = bx >> 7;
    int mt = (bx >> 1) & 63;      // nt fastest -> A-tile L2 reuse
    int nt = bx & 1;

    int t = threadIdx.x;
    int w = t >> 6, lane = t & 63;
    int l16 = lane & 15, kq = lane >> 4;
    int wm = w >> 1, wn = w & 1;

    f32x4 acc[4][4];
#pragma unroll
    for (int i = 0; i < 4; ++i)
#pragma unroll
        for (int j = 0; j < 4; ++j) acc[i][j] = (f32x4){0.f, 0.f, 0.f, 0.f};

    const short* Ag = hact + ((size_t)head * B_ + (size_t)mt * 128) * H_;
    const short* Bg = w2t  + ((size_t)head * D_ + (size_t)nt * 128) * H_;

    gemmc<8>(Ag, H_, Bg, H_, As, Bs, acc, t, wm * 64, wn * 64);

#pragma unroll
    for (int mf = 0; mf < 4; ++mf) {
        int m = mt * 128 + wm * 64 + mf * 16 + kq * 4;
#pragma unroll
        for (int nf = 0; nf < 4; ++nf) {
            int d = nt * 128 + wn * 64 + nf * 16 + l16;
#pragma unroll
            for (int r = 0; r < 4; ++r) {
                float v = acc[mf][nf][r]
                        + bf2f(pb[((size_t)head * B_ + m + r) * D_ + d]);
                out[(size_t)(m + r) * (N_ * D_) + head * D_ + d] = v;
            }
        }
    }
}

// ---------------------------------------------------------------------------
extern "C" void kernel_launch(void* const* d_in, const int* in_sizes, int n_in,
                              void* d_out, int out_size, void* d_ws, size_t ws_size,
                              hipStream_t stream) {
    const float* x   = (const float*)d_in[0];
    const float* n1w = (const float*)d_in[1];
    const float* n2w = (const float*)d_in[2];
    const float* w1  = (const float*)d_in[3];
    const float* w3  = (const float*)d_in[4];
    const float* w2  = (const float*)d_in[5];
    float* out = (float*)d_out;

    char* ws = (char*)d_ws;
    // ws layout (total ~268 MiB):
    short* wgu  = (short*)(ws);                       //  8 MiB (interleaved G/U)
    short* w2t  = (short*)(ws + (8ull   << 20));      //  4 MiB
    short* pn   = (short*)(ws + (12ull  << 20));      // 64 MiB (bf16, head-major)
    short* pb   = (short*)(ws + (76ull  << 20));      // 64 MiB (bf16, head-major)
    short* hact = (short*)(ws + (140ull << 20));      // 128 MiB (bf16, head-major)

    k_prep<<<(N_ * D_ * H_) / 256, 256, 0, stream>>>(w1, w3, w2, wgu, w2t);
    k_mix<<<B_, 256, 0, stream>>>(x, n1w, n2w,
                                  (unsigned int*)pb, (unsigned int*)pn);
    k_gu<<<N_ * (B_ / 128) * (1024 / 128), 256, 0, stream>>>(pn, wgu, hact);
    k_dn<<<N_ * (B_ / 128) * (D_ / 128), 256, 0, stream>>>(hact, w2t, pb, out);
}